// Round 4
// baseline (219.572 us; speedup 1.0000x reference)
//
#include <hip/hip_runtime.h>
#include <hip/hip_bf16.h>

// (T, H, O) = (32768, 1024, 1024)
constexpr int T = 32768;
constexpr int H = 1024;

constexpr int NW  = 4096;          // total waves in pass1 (16/CU)
constexpr int RPW = T / NW;        // 8 rows per wave
constexpr int NB1 = NW / 4;        // 1024 blocks of 256 threads (4 waves)

// ws layout (floats)
constexpr int MW_OFF   = 0;                    // per-wave running max  (NW)
constexpr int LW_OFF   = NW;                   // per-wave running sum  (NW)
constexpr int SC_OFF   = 2 * NW;               // raw scores (T)
constexpr int PART_OFF = 2 * NW + T;           // per-wave partial outputs (NW*H)

// ---------------- Pass 1: one wave per row, barrier-free online softmax -----
// Lane covers columns {p*256 + lane*4 .. +3 : p=0..3}. Wave-private (m,l,acc)
// over its 8 rows; enc element read from HBM exactly once, used for both the
// score dot and the weighted accumulation. No LDS, no __syncthreads.
__global__ __launch_bounds__(256) void pass1(
    const float* __restrict__ enc, const float* __restrict__ w_enc,
    float* __restrict__ scores, float* __restrict__ mw, float* __restrict__ lw,
    float* __restrict__ parts, float* __restrict__ out) {
    const int tid   = threadIdx.x;
    const int lane  = tid & 63;
    const int gwave = blockIdx.x * 4 + (tid >> 6);
    const int row0  = gwave * RPW;

    if (blockIdx.x < 4) out[blockIdx.x * 256 + tid] = 0.f;  // d_out zero-init

    float4 w[4];
#pragma unroll
    for (int p = 0; p < 4; ++p)
        w[p] = *reinterpret_cast<const float4*>(w_enc + p * 256 + lane * 4);

    float  m = -3.0e38f, l = 0.f;
    float4 acc[4];
#pragma unroll
    for (int p = 0; p < 4; ++p) acc[p] = make_float4(0.f, 0.f, 0.f, 0.f);

#pragma unroll 2
    for (int r = 0; r < RPW; ++r) {
        const float* rp = enc + (size_t)(row0 + r) * H;
        float4 e[4];
#pragma unroll
        for (int p = 0; p < 4; ++p)
            e[p] = *reinterpret_cast<const float4*>(rp + p * 256 + lane * 4);

        float s = 0.f;
#pragma unroll
        for (int p = 0; p < 4; ++p)
            s += e[p].x * w[p].x + e[p].y * w[p].y + e[p].z * w[p].z + e[p].w * w[p].w;
#pragma unroll
        for (int off = 32; off; off >>= 1) s += __shfl_xor(s, off);

        if (lane == 0) scores[row0 + r] = s;

        if (s > m) {                        // wave-uniform branch (s uniform)
            const float rs = __expf(m - s); // first row: exp(-inf) -> 0
            l *= rs;
#pragma unroll
            for (int p = 0; p < 4; ++p) {
                acc[p].x *= rs; acc[p].y *= rs; acc[p].z *= rs; acc[p].w *= rs;
            }
            m = s;
        }
        const float wgt = __expf(s - m);
        l += wgt;
#pragma unroll
        for (int p = 0; p < 4; ++p) {
            acc[p].x = fmaf(wgt, e[p].x, acc[p].x);
            acc[p].y = fmaf(wgt, e[p].y, acc[p].y);
            acc[p].z = fmaf(wgt, e[p].z, acc[p].z);
            acc[p].w = fmaf(wgt, e[p].w, acc[p].w);
        }
    }

#pragma unroll
    for (int p = 0; p < 4; ++p)
        *reinterpret_cast<float4*>(parts + (size_t)gwave * H + p * 256 + lane * 4) = acc[p];
    if (lane == 0) { mw[gwave] = m; lw[gwave] = l; }
}

// ---------------- Pass 2: redundant (M,L), combine partials, weights --------
// Every block recomputes global M,L from mw/lw (32 KB, L2/L3-hot).
// blocks 0..127 : out[h] += 32 rescaled partial vectors (atomic)
// blocks 128..159: normalized weights, 1024 t-values each
__global__ __launch_bounds__(256) void combine(
    const float* __restrict__ mw, const float* __restrict__ lw,
    const float* __restrict__ parts, const float* __restrict__ scores,
    float* __restrict__ out, float* __restrict__ wout) {
    __shared__ float sm[8];
    const int tid  = threadIdx.x;
    const int wv   = tid >> 6;
    const int lane = tid & 63;

    float m = -3.0e38f;
#pragma unroll 4
    for (int i = tid; i < NW; i += 256) m = fmaxf(m, mw[i]);
#pragma unroll
    for (int off = 32; off; off >>= 1) m = fmaxf(m, __shfl_xor(m, off));
    if (lane == 0) sm[wv] = m;
    __syncthreads();
    const float M = fmaxf(fmaxf(sm[0], sm[1]), fmaxf(sm[2], sm[3]));

    float l = 0.f;
#pragma unroll 4
    for (int i = tid; i < NW; i += 256) l += lw[i] * __expf(mw[i] - M);
#pragma unroll
    for (int off = 32; off; off >>= 1) l += __shfl_xor(l, off);
    if (lane == 0) sm[4 + wv] = l;
    __syncthreads();
    const float rL = 1.f / (sm[4] + sm[5] + sm[6] + sm[7]);

    if (blockIdx.x < 128) {
        const int w0 = blockIdx.x * 32;
        float4 a = make_float4(0.f, 0.f, 0.f, 0.f);
#pragma unroll 4
        for (int i = 0; i < 32; ++i) {
            const float c = __expf(mw[w0 + i] - M) * rL;
            float4 v = *reinterpret_cast<const float4*>(parts + (size_t)(w0 + i) * H + tid * 4);
            a.x = fmaf(c, v.x, a.x);
            a.y = fmaf(c, v.y, a.y);
            a.z = fmaf(c, v.z, a.z);
            a.w = fmaf(c, v.w, a.w);
        }
        atomicAdd(&out[4 * tid + 0], a.x);
        atomicAdd(&out[4 * tid + 1], a.y);
        atomicAdd(&out[4 * tid + 2], a.z);
        atomicAdd(&out[4 * tid + 3], a.w);
    } else {
        const int t0 = (blockIdx.x - 128) * 1024 + 4 * tid;
        float4 sv = *reinterpret_cast<const float4*>(scores + t0);
        float4 wvout;
        wvout.x = __expf(sv.x - M) * rL;
        wvout.y = __expf(sv.y - M) * rL;
        wvout.z = __expf(sv.z - M) * rL;
        wvout.w = __expf(sv.w - M) * rL;
        *reinterpret_cast<float4*>(wout + t0) = wvout;
    }
}

extern "C" void kernel_launch(void* const* d_in, const int* in_sizes, int n_in,
                              void* d_out, int out_size, void* d_ws, size_t ws_size,
                              hipStream_t stream) {
    // inputs: dec_h (1024), enc (T*H), attn_w (2048), attn_b (1)
    // dec_h/attn_b shift all scores by one constant -> cancels in softmax.
    const float* enc    = (const float*)d_in[1];
    const float* attn_w = (const float*)d_in[2];
    const float* w_enc  = attn_w + 1024;

    float* out  = (float*)d_out;       // [0..H): output vector
    float* wout = (float*)d_out + H;   // [H..H+T): normalized weights

    float* ws     = (float*)d_ws;
    float* mw     = ws + MW_OFF;
    float* lw     = ws + LW_OFF;
    float* scores = ws + SC_OFF;
    float* parts  = ws + PART_OFF;

    pass1<<<NB1, 256, 0, stream>>>(enc, w_enc, scores, mw, lw, parts, out);
    combine<<<160, 256, 0, stream>>>(mw, lw, parts, scores, out, wout);
}